// Round 13
// baseline (302.723 us; speedup 1.0000x reference)
//
#include <hip/hip_runtime.h>

// Problem constants (fixed by the reference)
#define Bn   4
#define Tn   512
#define Pn   3
#define HIDn 512
#define HDn  32
#define Hn   16
#define EXPn 512
#define Sn   1024
#define Dn   96          // per-head dim = P*HD
#define LOG2E 1.44269504088896340736f
#define CH   32          // s-cols per chunk
#define NC2  ((Sn / 2) / CH)   // 16 chunks per s-half

// prep-kernel block ranges
#define NBLK_KQ (Bn * Hn * 8)                  // 512  (k/q pack, 128 s each)
#define NBLK_V  (Bn * Hn * 16)                 // 1024
#define NBLK_W  ((HIDn * HIDn) / (256 * 8))    // 128
#define NBLK_LW ((Bn * Tn * Sn) / (256 * 8))   // 1024

typedef __bf16 bf16_t;
typedef __bf16 bf16x8 __attribute__((ext_vector_type(8)));
typedef __bf16 bf16x4 __attribute__((ext_vector_type(4)));
typedef float  f32x4  __attribute__((ext_vector_type(4)));

#define GLDS(g, l) __builtin_amdgcn_global_load_lds(                            \
    (const __attribute__((address_space(1))) void*)(g),                         \
    (__attribute__((address_space(3))) void*)(l), 16, 0, 0)

// ---------------------------------------------------------------------------
// prep: pack k/q (R17 coalesced layout) + pack_v + pack_w(lnw-folded) +
// lw -> masked bf16 Lb (R15-verified range: mask decided in f32 exactly as
// reference, bf16 only affects the p*lw product).  No sumsq (combine_ln
// computes the RMS directly now).
//   blocks [0, 512)         : pack k (+q for s0<512 chunks)
//   blocks [512, 1536)      : pack_v
//   blocks [1536, 1664)     : pack_w
//   blocks [1664, 2688)     : lw -> Lb bf16 (pre-masked)
// ---------------------------------------------------------------------------
__global__ __launch_bounds__(256) void prep(
    const float* __restrict__ q, const float* __restrict__ k,
    const float* __restrict__ v, const int* __restrict__ outcell,
    const float* __restrict__ W, const float* __restrict__ lnw,
    const float* __restrict__ lw,
    bf16_t* __restrict__ Qh, bf16_t* __restrict__ Kh,
    bf16_t* __restrict__ Vt, bf16_t* __restrict__ Wb,
    bf16_t* __restrict__ Lb)
{
    const int blk = blockIdx.x;
    const int tid = threadIdx.x;
    __shared__ float tile[64 * 108];
    __shared__ int ts_sh[128];

    if (blk < NBLK_KQ) {
        // ============ pack k (+q): coalesced (b,h,s-chunk) layout ==========
        const int b = blk >> 7;
        const int h = (blk >> 3) & 15;
        const int s0 = (blk & 7) << 7;
        if (tid < 128) {
            const int s = s0 + tid;
            ts_sh[tid] = (s < Tn) ? s : outcell[b * EXPn + (s - Tn)];
        }
        __syncthreads();
        const size_t bh = (size_t)b * Hn + h;
#pragma unroll
        for (int j = 0; j < 12; ++j) {
            const int u = tid + 256 * j;
            const int sl = u / 24, c = u % 24;
            const int p = c >> 3, f = c & 7;
            float4 val = *(const float4*)&k[(size_t)(b * Tn + ts_sh[sl]) * (Pn * HIDn)
                                            + p * HIDn + h * HDn + f * 4];
            bf16_t o4[4] = {(bf16_t)val.x, (bf16_t)val.y, (bf16_t)val.z, (bf16_t)val.w};
            *(uint2*)&Kh[(bh * Sn + s0 + sl) * Dn + c * 4] = *(uint2*)o4;
        }
        if (s0 < Tn) {
#pragma unroll
            for (int j = 0; j < 12; ++j) {
                const int u = tid + 256 * j;
                const int sl = u / 24, c = u % 24;
                const int p = c >> 3, f = c & 7;
                float4 val = *(const float4*)&q[(size_t)(b * Tn + s0 + sl) * (Pn * HIDn)
                                                + p * HIDn + h * HDn + f * 4];
                bf16_t o4[4] = {(bf16_t)(val.x * LOG2E), (bf16_t)(val.y * LOG2E),
                                (bf16_t)(val.z * LOG2E), (bf16_t)(val.w * LOG2E)};
                *(uint2*)&Qh[(bh * Tn + s0 + sl) * Dn + c * 4] = *(uint2*)o4;
            }
        }
    } else if (blk < NBLK_KQ + NBLK_V) {
        // ============ pack_v (R3/R4-verified body) =========================
        const int vblk = blk - NBLK_KQ;
        const int bh = vblk >> 4, s0 = (vblk & 15) << 6;
        const int b = bh >> 4, h = bh & 15;
        if (tid < 64) {
            const int s = s0 + tid;
            ts_sh[tid] = (s < Tn) ? s : outcell[b * EXPn + (s - Tn)];
        }
        __syncthreads();
        for (int u = tid; u < 64 * 24; u += 256) {
            const int sl = u / 24, c = u % 24;
            const int p = c >> 3, f = c & 7;
            float4 val = *(const float4*)&v[(size_t)(b * Tn + ts_sh[sl]) * (Pn * HIDn)
                                            + p * HIDn + h * HDn + f * 4];
            *(float4*)&tile[sl * 108 + c * 4] = val;
        }
        __syncthreads();
        for (int e = tid; e < 96 * 8; e += 256) {
            const int d = e >> 3, g = e & 7;
            bf16_t o8[8];
#pragma unroll
            for (int j = 0; j < 8; ++j) o8[j] = (bf16_t)tile[(g * 8 + j) * 108 + d];
            *(uint4*)&Vt[((size_t)bh * Dn + d) * Sn + s0 + g * 8] = *(uint4*)o8;
        }
    } else if (blk < NBLK_KQ + NBLK_V + NBLK_W) {
        // ============ pack_w (lnw folded) ==================================
        const int wblk = blk - (NBLK_KQ + NBLK_V);
        const int i = wblk * 256 + tid;
        const int d0 = (i * 8) & 511;
        float4 f0 = *(const float4*)&W[i * 8];
        float4 f1 = *(const float4*)&W[i * 8 + 4];
        float4 l0 = *(const float4*)&lnw[d0];
        float4 l1 = *(const float4*)&lnw[d0 + 4];
        bf16_t o8[8] = {(bf16_t)(f0.x * l0.x), (bf16_t)(f0.y * l0.y),
                        (bf16_t)(f0.z * l0.z), (bf16_t)(f0.w * l0.w),
                        (bf16_t)(f1.x * l1.x), (bf16_t)(f1.y * l1.y),
                        (bf16_t)(f1.z * l1.z), (bf16_t)(f1.w * l1.w)};
        *(uint4*)&Wb[i * 8] = *(uint4*)o8;
    } else {
        // ============ lw (f32) -> Lb (bf16, pre-masked) ====================
        const int w2 = blk - (NBLK_KQ + NBLK_V + NBLK_W);
        const size_t i = ((size_t)w2 * 256 + tid) * 8;
        float4 f0 = *(const float4*)&lw[i];
        float4 f1 = *(const float4*)&lw[i + 4];
        const float m0 = (f0.x <= 1e-5f) ? 0.f : f0.x;
        const float m1 = (f0.y <= 1e-5f) ? 0.f : f0.y;
        const float m2 = (f0.z <= 1e-5f) ? 0.f : f0.z;
        const float m3 = (f0.w <= 1e-5f) ? 0.f : f0.w;
        const float m4 = (f1.x <= 1e-5f) ? 0.f : f1.x;
        const float m5 = (f1.y <= 1e-5f) ? 0.f : f1.y;
        const float m6 = (f1.z <= 1e-5f) ? 0.f : f1.z;
        const float m7 = (f1.w <= 1e-5f) ? 0.f : f1.w;
        bf16_t o8[8] = {(bf16_t)m0, (bf16_t)m1, (bf16_t)m2, (bf16_t)m3,
                        (bf16_t)m4, (bf16_t)m5, (bf16_t)m6, (bf16_t)m7};
        *(uint4*)&Lb[i] = *(uint4*)o8;
    }
}

// ---------------------------------------------------------------------------
// attn_kernel R18: 3 blocks/CU via LDS-slim + s-split x2.
// R12/R16 loop body (verified) with: bias depth 2, lw as bf16 Lb (read
// formula R15-verified), s-half per blockIdx.z (16 chunks), unnormalized
// partial (Po f32, Pl) output merged by combine_ln (R9-verified pattern).
// LDS 54,272 B -> 3 blocks/CU; grid 1024 blocks -> the first time this
// kernel runs >8 waves/CU.  6 GLDS/wave/chunk (3 KV + 2 bias + 1 lw):
// steady vmcnt(6), tail vmcnt(0).
// ---------------------------------------------------------------------------
__global__ __launch_bounds__(256, 2) void attn_kernel(
    const bf16_t* __restrict__ Qh, const bf16_t* __restrict__ Kh,
    const bf16_t* __restrict__ Vt, const float* __restrict__ bias,
    const bf16_t* __restrict__ Lb, float* __restrict__ Po,
    float* __restrict__ Pl)
{
    const int h  = blockIdx.x;
    const int b  = blockIdx.y >> 3;
    const int t0 = (blockIdx.y & 7) << 6;
    const int sg = blockIdx.z;            // s-half
    const int tid = threadIdx.x;
    const int wv  = tid >> 6;
    const int lane = tid & 63;
    const int l16 = lane & 15;
    const int quad = lane >> 4;

    __shared__ bf16_t KfS[2][6][512];     // K frags f=ct*3+ks   (12 KB)
    __shared__ bf16_t VfS[2][6][512];     // V frags f=dt        (12 KB)
    __shared__ float  BfS[2][4][2][256];  // bias [buf][wv][ct]  (16 KB)
    __shared__ bf16_t LwS[2][4][512];     // lw bf16 [buf][wv]    (8 KB)
    __shared__ bf16_t Ps[4][16 * 40];     // P transpose          (5 KB)

    const size_t bh = (size_t)b * Hn + h;
    const int tb = t0 + wv * 16;
    const int sbase = sg * (Sn / 2);

    bf16x8 qf[3];
    {
        const bf16_t* qb = Qh + (bh * Tn + tb + l16) * Dn + quad * 8;
#pragma unroll
        for (int ks = 0; ks < 3; ++ks) qf[ks] = *(const bf16x8*)(qb + ks * 32);
    }
    asm volatile("s_waitcnt vmcnt(0)" ::: "memory");

    int kA, kB, two_k, vA, vB;
    if (wv == 0)      { kA = 0; kB = 1; two_k = 1; vA = 0; vB = 0; }
    else if (wv == 1) { kA = 2; kB = 3; two_k = 1; vA = 1; vB = 0; }
    else if (wv == 2) { kA = 4; kB = 4; two_k = 0; vA = 2; vB = 3; }
    else              { kA = 5; kB = 5; two_k = 0; vA = 4; vB = 5; }

    const float*  gB  = bias + (bh * Tn + tb + l16) * (size_t)Sn + quad * 4;
    const bf16_t* gLw = Lb + ((size_t)b * Tn + tb + l16) * Sn + quad * 8;
    const bf16_t* gKA = Kh + (bh * Sn + (kA / 3) * 16 + l16) * (size_t)Dn + (kA % 3) * 32 + quad * 8;
    const bf16_t* gKB = Kh + (bh * Sn + (kB / 3) * 16 + l16) * (size_t)Dn + (kB % 3) * 32 + quad * 8;
    const bf16_t* gVA = Vt + (bh * Dn + vA * 16 + l16) * (size_t)Sn + quad * 8;
    const bf16_t* gVB = Vt + (bh * Dn + vB * 16 + l16) * (size_t)Sn + quad * 8;

    auto stage_kv = [&](int s0, int buf) {
        GLDS(gKA + (size_t)s0 * Dn, &KfS[buf][kA][0]);
        if (two_k) GLDS(gKB + (size_t)s0 * Dn, &KfS[buf][kB][0]);
        GLDS(gVA + s0, &VfS[buf][vA][0]);
        if (!two_k) GLDS(gVB + s0, &VfS[buf][vB][0]);
    };
    auto stage_bl = [&](int s0, int buf) {
        GLDS(gB + s0,      &BfS[buf][wv][0][0]);
        GLDS(gB + s0 + 16, &BfS[buf][wv][1][0]);
        GLDS(gLw + s0,     &LwS[buf][wv][0]);
    };

    f32x4 Oacc[6];
#pragma unroll
    for (int i = 0; i < 6; ++i) Oacc[i] = f32x4{0.f, 0.f, 0.f, 0.f};
    float lacc = 0.f;

    stage_kv(sbase, 0);
    stage_bl(sbase, 0);

    for (int c = 0; c < NC2; ++c) {
        const int buf = c & 1;
        const int s0 = sbase + c * CH;
        __builtin_amdgcn_sched_barrier(0);
        __builtin_amdgcn_s_barrier();
        __builtin_amdgcn_sched_barrier(0);
        if (c + 1 < NC2) {
            stage_kv(s0 + CH, buf ^ 1);
            stage_bl(s0 + CH, buf ^ 1);
            asm volatile("s_waitcnt vmcnt(6)" ::: "memory");   // chunk c landed
        } else {
            asm volatile("s_waitcnt vmcnt(0)" ::: "memory");
        }
        __builtin_amdgcn_s_barrier();
        __builtin_amdgcn_sched_barrier(0);

        // ---- pull bias (f32x4) and lw (bf16x4, R15-verified formula)
        f32x4 BR[2];
        BR[0] = *(const f32x4*)&BfS[buf][wv][0][lane * 4];
        BR[1] = *(const f32x4*)&BfS[buf][wv][1][lane * 4];
        bf16x4 lw4[2];
#pragma unroll
        for (int ct = 0; ct < 2; ++ct)
            lw4[ct] = *(const bf16x4*)&LwS[buf][wv][((ct * 2 + (quad >> 1)) * 16 + l16) * 8 + (quad & 1) * 4];

        // ---- QK^T swapped (setprio-wrapped)
        f32x4 sc[2];
        __builtin_amdgcn_s_setprio(1);
#pragma unroll
        for (int ct = 0; ct < 2; ++ct) {
            f32x4 acc = f32x4{0.f, 0.f, 0.f, 0.f};
#pragma unroll
            for (int ks = 0; ks < 3; ++ks) {
                bf16x8 kf = *(const bf16x8*)&KfS[buf][ct * 3 + ks][lane * 8];
                acc = __builtin_amdgcn_mfma_f32_16x16x32_bf16(kf, qf[ks], acc, 0, 0, 0);
            }
            sc[ct] = acc;
        }
        __builtin_amdgcn_s_setprio(0);

        // ---- p = exp2(sc + bias*LOG2E); masked (lw==0) -> exact 0
        float lsum = 0.f;
#pragma unroll
        for (int ct = 0; ct < 2; ++ct) {
            bf16_t o4[4];
#pragma unroll
            for (int r = 0; r < 4; ++r) {
                const float lwf = (float)lw4[ct][r];
                const float wval = __builtin_fmaf(BR[ct][r], LOG2E, sc[ct][r]);
                const float pe = (lwf > 0.f) ? exp2f(wval) : 0.f;
                lsum += pe;
                o4[r] = (bf16_t)(pe * lwf);
            }
            *(uint2*)&Ps[wv][l16 * 40 + ct * 16 + quad * 4] = *(uint2*)o4;
        }
        lacc += lsum;

        // ---- PV swapped (setprio-wrapped)
        bf16x8 pb = *(const bf16x8*)&Ps[wv][l16 * 40 + quad * 8];
        __builtin_amdgcn_s_setprio(1);
#pragma unroll
        for (int dt = 0; dt < 6; ++dt) {
            bf16x8 vf = *(const bf16x8*)&VfS[buf][dt][lane * 8];
            Oacc[dt] = __builtin_amdgcn_mfma_f32_16x16x32_bf16(vf, pb, Oacc[dt], 0, 0, 0);
        }
        __builtin_amdgcn_s_setprio(0);
    }

    // ---- write partials (unnormalized O + l)  [R9-verified pattern]
    lacc += __shfl_xor(lacc, 16);
    lacc += __shfl_xor(lacc, 32);
    const size_t row_id = ((size_t)(sg * Bn + b) * Hn + h) * Tn + tb + l16;
#pragma unroll
    for (int dt = 0; dt < 6; ++dt)
        *(f32x4*)&Po[row_id * 96 + dt * 16 + quad * 4] = Oacc[dt];
    if (quad == 0) Pl[row_id] = lacc;
}

// ---------------------------------------------------------------------------
// combine_ln (R9-verified body, lnw removed -- folded into Wb): one block
// per (b,t).  O = (O0+O1)/(l0+l1); sumsq over 16h x 96d without atomics;
// writes xln/rms directly as bf16 Xb for the GEMM.
// ---------------------------------------------------------------------------
__global__ __launch_bounds__(256) void combine_ln(
    const float* __restrict__ Po, const float* __restrict__ Pl,
    bf16_t* __restrict__ Xb)
{
    const int bt = blockIdx.x;            // b*Tn + t
    const int tid = threadIdx.x;
    const int hh = tid >> 4;              // head 0..15
    const int d0 = (tid & 15) * 6;        // 6 dims per thread
    const int b = bt >> 9, t = bt & 511;
    const size_t half = (size_t)Bn * Hn * Tn;
    const size_t row = ((size_t)b * Hn + hh) * Tn + t;

    const float invl = 1.0f / (Pl[row] + Pl[half + row]);

    float o[6];
    float ss = 0.f;
    {
        const float* p0 = &Po[row * 96 + d0];
        const float* p1 = &Po[(half + row) * 96 + d0];
#pragma unroll
        for (int j = 0; j < 6; ++j) {
            o[j] = (p0[j] + p1[j]) * invl;
            ss += o[j] * o[j];
        }
    }
    __shared__ float red[4];
#pragma unroll
    for (int off = 1; off < 64; off <<= 1) ss += __shfl_xor(ss, off);
    if ((tid & 63) == 0) red[tid >> 6] = ss;
    __syncthreads();
    const float tot = red[0] + red[1] + red[2] + red[3];
    const float inv = rsqrtf(tot * (1.0f / HIDn) + 1e-3f);

#pragma unroll
    for (int j = 0; j < 6; ++j) {
        const int d = d0 + j;
        const int p = d >> 5, hid = hh * 32 + (d & 31);
        Xb[((size_t)bt * Pn + p) * HIDn + hid] = (bf16_t)(o[j] * inv);
    }
}

// ---------------------------------------------------------------------------
// out_gemm (R16 async structure, sumsq/invm removed): pure bf16 GEMM
// out[m,n] = sum_k Xb[m,k] * Wb[n,k]  (lnw and rms already applied).
// ---------------------------------------------------------------------------
__global__ __launch_bounds__(256, 2) void out_gemm(
    const bf16_t* __restrict__ Xb, const bf16_t* __restrict__ Wb,
    float* __restrict__ out)
{
    const int n0 = blockIdx.x * 64;
    const int m0 = blockIdx.y * 64;
    const int tid = threadIdx.x;
    const int wv = tid >> 6, lane = tid & 63, l16 = lane & 15, quad = lane >> 4;

    __shared__ bf16_t Af[2][8][512];   // A frag f = wv*2+ks  (16 KB)
    __shared__ bf16_t Bf[2][8][512];   // B frag f = nt*2+ks  (16 KB)

    const bf16_t* gA0 = Xb + (size_t)(m0 + wv * 16 + l16) * HIDn + 0 * 32 + quad * 8;
    const bf16_t* gA1 = Xb + (size_t)(m0 + wv * 16 + l16) * HIDn + 1 * 32 + quad * 8;
    const bf16_t* gB0 = Wb + (size_t)(n0 + wv * 16 + l16) * HIDn + 0 * 32 + quad * 8;
    const bf16_t* gB1 = Wb + (size_t)(n0 + wv * 16 + l16) * HIDn + 1 * 32 + quad * 8;

    auto stage = [&](int kc, int buf) {
        GLDS(gA0 + kc, &Af[buf][wv * 2 + 0][0]);
        GLDS(gA1 + kc, &Af[buf][wv * 2 + 1][0]);
        GLDS(gB0 + kc, &Bf[buf][wv * 2 + 0][0]);
        GLDS(gB1 + kc, &Bf[buf][wv * 2 + 1][0]);
    };

    f32x4 acc[4];
#pragma unroll
    for (int i = 0; i < 4; ++i) acc[i] = f32x4{0.f, 0.f, 0.f, 0.f};

    stage(0, 0);

    for (int c = 0; c < 8; ++c) {
        const int buf = c & 1;
        __builtin_amdgcn_sched_barrier(0);
        __builtin_amdgcn_s_barrier();
        __builtin_amdgcn_sched_barrier(0);
        if (c + 1 < 8) {
            stage((c + 1) * 64, buf ^ 1);
            asm volatile("s_waitcnt vmcnt(4)" ::: "memory");
        } else {
            asm volatile("s_waitcnt vmcnt(0)" ::: "memory");
        }
        __builtin_amdgcn_s_barrier();
        __builtin_amdgcn_sched_barrier(0);

        __builtin_amdgcn_s_setprio(1);
#pragma unroll
        for (int ks = 0; ks < 2; ++ks) {
            bf16x8 a = *(const bf16x8*)&Af[buf][wv * 2 + ks][lane * 8];
#pragma unroll
            for (int nt = 0; nt < 4; ++nt) {
                bf16x8 bb = *(const bf16x8*)&Bf[buf][nt * 2 + ks][lane * 8];
                acc[nt] = __builtin_amdgcn_mfma_f32_16x16x32_bf16(a, bb, acc[nt], 0, 0, 0);
            }
        }
        __builtin_amdgcn_s_setprio(0);
    }

#pragma unroll
    for (int nt = 0; nt < 4; ++nt)
#pragma unroll
        for (int r = 0; r < 4; ++r) {
            const int m = m0 + wv * 16 + quad * 4 + r;
            const int n = n0 + nt * 16 + l16;
            out[(size_t)m * HIDn + n] = acc[nt][r];
        }
}

// ---------------------------------------------------------------------------
// Workspace: Qh@0 (6291456) | Kh@6291456 (12582912) | Vt@18874368 (12582912) |
// Po@31457280 (25165824) | Pl@56623104 (262144) | Xb@56885248 (6291456) |
// Wb@63176704 (524288) | Lb@63700992 (4194304)  -- total 67,895,296
// ---------------------------------------------------------------------------
extern "C" void kernel_launch(void* const* d_in, const int* in_sizes, int n_in,
                              void* d_out, int out_size, void* d_ws, size_t ws_size,
                              hipStream_t stream)
{
    const float* q    = (const float*)d_in[0];
    const float* k    = (const float*)d_in[1];
    const float* v    = (const float*)d_in[2];
    const float* bias = (const float*)d_in[3];
    const int*   outcell = (const int*)d_in[5];
    const float* lw   = (const float*)d_in[6];
    const float* W    = (const float*)d_in[8];
    const float* lnw  = (const float*)d_in[9];
    float* out = (float*)d_out;

    char* ws = (char*)d_ws;
    bf16_t* Qh   = (bf16_t*)(ws);
    bf16_t* Kh   = (bf16_t*)(ws + 6291456);
    bf16_t* Vt   = (bf16_t*)(ws + 18874368);
    float*  Po   = (float*)(ws + 31457280);
    float*  Pl   = (float*)(ws + 56623104);
    bf16_t* Xb   = (bf16_t*)(ws + 56885248);
    bf16_t* Wb   = (bf16_t*)(ws + 63176704);
    bf16_t* Lb   = (bf16_t*)(ws + 63700992);

    prep<<<dim3(NBLK_KQ + NBLK_V + NBLK_W + NBLK_LW), 256, 0, stream>>>(
        q, k, v, outcell, W, lnw, lw, Qh, Kh, Vt, Wb, Lb);
    attn_kernel<<<dim3(Hn, Bn * (Tn / 64), 2), 256, 0, stream>>>(Qh, Kh, Vt, bias, Lb, Po, Pl);
    combine_ln<<<dim3(Bn * Tn), 256, 0, stream>>>(Po, Pl, Xb);
    out_gemm<<<dim3(HIDn / 64, (Bn * Tn * Pn) / 64), 256, 0, stream>>>(Xb, Wb, out);
}

// Round 14
// 297.014 us; speedup vs baseline: 1.0192x; 1.0192x over previous
//
#include <hip/hip_runtime.h>

// Problem constants (fixed by the reference)
#define Bn   4
#define Tn   512
#define Pn   3
#define HIDn 512
#define HDn  32
#define Hn   16
#define EXPn 512
#define Sn   1024
#define Dn   96          // per-head dim = P*HD
#define LOG2E 1.44269504088896340736f
#define CH   32          // s-cols per chunk
#define NC2  ((Sn / 2) / CH)   // 16 chunks per s-half

// prep-kernel block ranges
#define NBLK_KQ (Bn * Hn * 8)                  // 512  (k/q pack, 128 s each)
#define NBLK_V  (Bn * Hn * 16)                 // 1024
#define NBLK_W  ((HIDn * HIDn) / (256 * 8))    // 128
#define NBLK_LW ((Bn * Tn * Sn) / (256 * 8))   // 1024

typedef __bf16 bf16_t;
typedef __bf16 bf16x8 __attribute__((ext_vector_type(8)));
typedef __bf16 bf16x4 __attribute__((ext_vector_type(4)));
typedef float  f32x4  __attribute__((ext_vector_type(4)));

#define GLDS(g, l) __builtin_amdgcn_global_load_lds(                            \
    (const __attribute__((address_space(1))) void*)(g),                         \
    (__attribute__((address_space(3))) void*)(l), 16, 0, 0)

// ---------------------------------------------------------------------------
// prep: pack k/q (R17 coalesced layout) + pack_v + pack_w(lnw-folded) +
// lw -> masked bf16 Lb.  (R18-verified, unchanged)
//   blocks [0, 512)         : pack k (+q for s0<512 chunks)
//   blocks [512, 1536)      : pack_v
//   blocks [1536, 1664)     : pack_w
//   blocks [1664, 2688)     : lw -> Lb bf16 (pre-masked)
// ---------------------------------------------------------------------------
__global__ __launch_bounds__(256) void prep(
    const float* __restrict__ q, const float* __restrict__ k,
    const float* __restrict__ v, const int* __restrict__ outcell,
    const float* __restrict__ W, const float* __restrict__ lnw,
    const float* __restrict__ lw,
    bf16_t* __restrict__ Qh, bf16_t* __restrict__ Kh,
    bf16_t* __restrict__ Vt, bf16_t* __restrict__ Wb,
    bf16_t* __restrict__ Lb)
{
    const int blk = blockIdx.x;
    const int tid = threadIdx.x;
    __shared__ float tile[64 * 108];
    __shared__ int ts_sh[128];

    if (blk < NBLK_KQ) {
        const int b = blk >> 7;
        const int h = (blk >> 3) & 15;
        const int s0 = (blk & 7) << 7;
        if (tid < 128) {
            const int s = s0 + tid;
            ts_sh[tid] = (s < Tn) ? s : outcell[b * EXPn + (s - Tn)];
        }
        __syncthreads();
        const size_t bh = (size_t)b * Hn + h;
#pragma unroll
        for (int j = 0; j < 12; ++j) {
            const int u = tid + 256 * j;
            const int sl = u / 24, c = u % 24;
            const int p = c >> 3, f = c & 7;
            float4 val = *(const float4*)&k[(size_t)(b * Tn + ts_sh[sl]) * (Pn * HIDn)
                                            + p * HIDn + h * HDn + f * 4];
            bf16_t o4[4] = {(bf16_t)val.x, (bf16_t)val.y, (bf16_t)val.z, (bf16_t)val.w};
            *(uint2*)&Kh[(bh * Sn + s0 + sl) * Dn + c * 4] = *(uint2*)o4;
        }
        if (s0 < Tn) {
#pragma unroll
            for (int j = 0; j < 12; ++j) {
                const int u = tid + 256 * j;
                const int sl = u / 24, c = u % 24;
                const int p = c >> 3, f = c & 7;
                float4 val = *(const float4*)&q[(size_t)(b * Tn + s0 + sl) * (Pn * HIDn)
                                                + p * HIDn + h * HDn + f * 4];
                bf16_t o4[4] = {(bf16_t)(val.x * LOG2E), (bf16_t)(val.y * LOG2E),
                                (bf16_t)(val.z * LOG2E), (bf16_t)(val.w * LOG2E)};
                *(uint2*)&Qh[(bh * Tn + s0 + sl) * Dn + c * 4] = *(uint2*)o4;
            }
        }
    } else if (blk < NBLK_KQ + NBLK_V) {
        const int vblk = blk - NBLK_KQ;
        const int bh = vblk >> 4, s0 = (vblk & 15) << 6;
        const int b = bh >> 4, h = bh & 15;
        if (tid < 64) {
            const int s = s0 + tid;
            ts_sh[tid] = (s < Tn) ? s : outcell[b * EXPn + (s - Tn)];
        }
        __syncthreads();
        for (int u = tid; u < 64 * 24; u += 256) {
            const int sl = u / 24, c = u % 24;
            const int p = c >> 3, f = c & 7;
            float4 val = *(const float4*)&v[(size_t)(b * Tn + ts_sh[sl]) * (Pn * HIDn)
                                            + p * HIDn + h * HDn + f * 4];
            *(float4*)&tile[sl * 108 + c * 4] = val;
        }
        __syncthreads();
        for (int e = tid; e < 96 * 8; e += 256) {
            const int d = e >> 3, g = e & 7;
            bf16_t o8[8];
#pragma unroll
            for (int j = 0; j < 8; ++j) o8[j] = (bf16_t)tile[(g * 8 + j) * 108 + d];
            *(uint4*)&Vt[((size_t)bh * Dn + d) * Sn + s0 + g * 8] = *(uint4*)o8;
        }
    } else if (blk < NBLK_KQ + NBLK_V + NBLK_W) {
        const int wblk = blk - (NBLK_KQ + NBLK_V);
        const int i = wblk * 256 + tid;
        const int d0 = (i * 8) & 511;
        float4 f0 = *(const float4*)&W[i * 8];
        float4 f1 = *(const float4*)&W[i * 8 + 4];
        float4 l0 = *(const float4*)&lnw[d0];
        float4 l1 = *(const float4*)&lnw[d0 + 4];
        bf16_t o8[8] = {(bf16_t)(f0.x * l0.x), (bf16_t)(f0.y * l0.y),
                        (bf16_t)(f0.z * l0.z), (bf16_t)(f0.w * l0.w),
                        (bf16_t)(f1.x * l1.x), (bf16_t)(f1.y * l1.y),
                        (bf16_t)(f1.z * l1.z), (bf16_t)(f1.w * l1.w)};
        *(uint4*)&Wb[i * 8] = *(uint4*)o8;
    } else {
        const int w2 = blk - (NBLK_KQ + NBLK_V + NBLK_W);
        const size_t i = ((size_t)w2 * 256 + tid) * 8;
        float4 f0 = *(const float4*)&lw[i];
        float4 f1 = *(const float4*)&lw[i + 4];
        const float m0 = (f0.x <= 1e-5f) ? 0.f : f0.x;
        const float m1 = (f0.y <= 1e-5f) ? 0.f : f0.y;
        const float m2 = (f0.z <= 1e-5f) ? 0.f : f0.z;
        const float m3 = (f0.w <= 1e-5f) ? 0.f : f0.w;
        const float m4 = (f1.x <= 1e-5f) ? 0.f : f1.x;
        const float m5 = (f1.y <= 1e-5f) ? 0.f : f1.y;
        const float m6 = (f1.z <= 1e-5f) ? 0.f : f1.z;
        const float m7 = (f1.w <= 1e-5f) ? 0.f : f1.w;
        bf16_t o8[8] = {(bf16_t)m0, (bf16_t)m1, (bf16_t)m2, (bf16_t)m3,
                        (bf16_t)m4, (bf16_t)m5, (bf16_t)m6, (bf16_t)m7};
        *(uint4*)&Lb[i] = *(uint4*)o8;
    }
}

// ---------------------------------------------------------------------------
// attn_kernel R19: R18 body UNCHANGED; __launch_bounds__(256, 3).
// R18 post-mortem: LDS 54,272 (3 blocks/CU fits), VGPR 68, grid 2048 --
// yet occupancy stayed 20% = 2 blocks/CU.  Across all rounds measured
// occupancy has EXACTLY tracked the 2nd launch_bounds arg ((256,2)->20%,
// (512,4)->40%, (256,8)->73-80%, (128,2)->21%): the waves-per-EU hint is
// acting as the occupancy cap.  R19 raises it to 3 (VGPR cap 512/3=170 >>
// 68, no spill risk) -- the first config where a 3rd independent block/CU
// is actually allowed.  Single-variable A/B on the cap theory.
// ---------------------------------------------------------------------------
__global__ __launch_bounds__(256, 3) void attn_kernel(
    const bf16_t* __restrict__ Qh, const bf16_t* __restrict__ Kh,
    const bf16_t* __restrict__ Vt, const float* __restrict__ bias,
    const bf16_t* __restrict__ Lb, float* __restrict__ Po,
    float* __restrict__ Pl)
{
    const int h  = blockIdx.x;
    const int b  = blockIdx.y >> 3;
    const int t0 = (blockIdx.y & 7) << 6;
    const int sg = blockIdx.z;            // s-half
    const int tid = threadIdx.x;
    const int wv  = tid >> 6;
    const int lane = tid & 63;
    const int l16 = lane & 15;
    const int quad = lane >> 4;

    __shared__ bf16_t KfS[2][6][512];     // K frags f=ct*3+ks   (12 KB)
    __shared__ bf16_t VfS[2][6][512];     // V frags f=dt        (12 KB)
    __shared__ float  BfS[2][4][2][256];  // bias [buf][wv][ct]  (16 KB)
    __shared__ bf16_t LwS[2][4][512];     // lw bf16 [buf][wv]    (8 KB)
    __shared__ bf16_t Ps[4][16 * 40];     // P transpose          (5 KB)

    const size_t bh = (size_t)b * Hn + h;
    const int tb = t0 + wv * 16;
    const int sbase = sg * (Sn / 2);

    bf16x8 qf[3];
    {
        const bf16_t* qb = Qh + (bh * Tn + tb + l16) * Dn + quad * 8;
#pragma unroll
        for (int ks = 0; ks < 3; ++ks) qf[ks] = *(const bf16x8*)(qb + ks * 32);
    }
    asm volatile("s_waitcnt vmcnt(0)" ::: "memory");

    int kA, kB, two_k, vA, vB;
    if (wv == 0)      { kA = 0; kB = 1; two_k = 1; vA = 0; vB = 0; }
    else if (wv == 1) { kA = 2; kB = 3; two_k = 1; vA = 1; vB = 0; }
    else if (wv == 2) { kA = 4; kB = 4; two_k = 0; vA = 2; vB = 3; }
    else              { kA = 5; kB = 5; two_k = 0; vA = 4; vB = 5; }

    const float*  gB  = bias + (bh * Tn + tb + l16) * (size_t)Sn + quad * 4;
    const bf16_t* gLw = Lb + ((size_t)b * Tn + tb + l16) * Sn + quad * 8;
    const bf16_t* gKA = Kh + (bh * Sn + (kA / 3) * 16 + l16) * (size_t)Dn + (kA % 3) * 32 + quad * 8;
    const bf16_t* gKB = Kh + (bh * Sn + (kB / 3) * 16 + l16) * (size_t)Dn + (kB % 3) * 32 + quad * 8;
    const bf16_t* gVA = Vt + (bh * Dn + vA * 16 + l16) * (size_t)Sn + quad * 8;
    const bf16_t* gVB = Vt + (bh * Dn + vB * 16 + l16) * (size_t)Sn + quad * 8;

    auto stage_kv = [&](int s0, int buf) {
        GLDS(gKA + (size_t)s0 * Dn, &KfS[buf][kA][0]);
        if (two_k) GLDS(gKB + (size_t)s0 * Dn, &KfS[buf][kB][0]);
        GLDS(gVA + s0, &VfS[buf][vA][0]);
        if (!two_k) GLDS(gVB + s0, &VfS[buf][vB][0]);
    };
    auto stage_bl = [&](int s0, int buf) {
        GLDS(gB + s0,      &BfS[buf][wv][0][0]);
        GLDS(gB + s0 + 16, &BfS[buf][wv][1][0]);
        GLDS(gLw + s0,     &LwS[buf][wv][0]);
    };

    f32x4 Oacc[6];
#pragma unroll
    for (int i = 0; i < 6; ++i) Oacc[i] = f32x4{0.f, 0.f, 0.f, 0.f};
    float lacc = 0.f;

    stage_kv(sbase, 0);
    stage_bl(sbase, 0);

    for (int c = 0; c < NC2; ++c) {
        const int buf = c & 1;
        const int s0 = sbase + c * CH;
        __builtin_amdgcn_sched_barrier(0);
        __builtin_amdgcn_s_barrier();
        __builtin_amdgcn_sched_barrier(0);
        if (c + 1 < NC2) {
            stage_kv(s0 + CH, buf ^ 1);
            stage_bl(s0 + CH, buf ^ 1);
            asm volatile("s_waitcnt vmcnt(6)" ::: "memory");   // chunk c landed
        } else {
            asm volatile("s_waitcnt vmcnt(0)" ::: "memory");
        }
        __builtin_amdgcn_s_barrier();
        __builtin_amdgcn_sched_barrier(0);

        // ---- pull bias (f32x4) and lw (bf16x4, R15-verified formula)
        f32x4 BR[2];
        BR[0] = *(const f32x4*)&BfS[buf][wv][0][lane * 4];
        BR[1] = *(const f32x4*)&BfS[buf][wv][1][lane * 4];
        bf16x4 lw4[2];
#pragma unroll
        for (int ct = 0; ct < 2; ++ct)
            lw4[ct] = *(const bf16x4*)&LwS[buf][wv][((ct * 2 + (quad >> 1)) * 16 + l16) * 8 + (quad & 1) * 4];

        // ---- QK^T swapped (setprio-wrapped)
        f32x4 sc[2];
        __builtin_amdgcn_s_setprio(1);
#pragma unroll
        for (int ct = 0; ct < 2; ++ct) {
            f32x4 acc = f32x4{0.f, 0.f, 0.f, 0.f};
#pragma unroll
            for (int ks = 0; ks < 3; ++ks) {
                bf16x8 kf = *(const bf16x8*)&KfS[buf][ct * 3 + ks][lane * 8];
                acc = __builtin_amdgcn_mfma_f32_16x16x32_bf16(kf, qf[ks], acc, 0, 0, 0);
            }
            sc[ct] = acc;
        }
        __builtin_amdgcn_s_setprio(0);

        // ---- p = exp2(sc + bias*LOG2E); masked (lw==0) -> exact 0
        float lsum = 0.f;
#pragma unroll
        for (int ct = 0; ct < 2; ++ct) {
            bf16_t o4[4];
#pragma unroll
            for (int r = 0; r < 4; ++r) {
                const float lwf = (float)lw4[ct][r];
                const float wval = __builtin_fmaf(BR[ct][r], LOG2E, sc[ct][r]);
                const float pe = (lwf > 0.f) ? exp2f(wval) : 0.f;
                lsum += pe;
                o4[r] = (bf16_t)(pe * lwf);
            }
            *(uint2*)&Ps[wv][l16 * 40 + ct * 16 + quad * 4] = *(uint2*)o4;
        }
        lacc += lsum;

        // ---- PV swapped (setprio-wrapped)
        bf16x8 pb = *(const bf16x8*)&Ps[wv][l16 * 40 + quad * 8];
        __builtin_amdgcn_s_setprio(1);
#pragma unroll
        for (int dt = 0; dt < 6; ++dt) {
            bf16x8 vf = *(const bf16x8*)&VfS[buf][dt][lane * 8];
            Oacc[dt] = __builtin_amdgcn_mfma_f32_16x16x32_bf16(vf, pb, Oacc[dt], 0, 0, 0);
        }
        __builtin_amdgcn_s_setprio(0);
    }

    // ---- write partials (unnormalized O + l)  [R9-verified pattern]
    lacc += __shfl_xor(lacc, 16);
    lacc += __shfl_xor(lacc, 32);
    const size_t row_id = ((size_t)(sg * Bn + b) * Hn + h) * Tn + tb + l16;
#pragma unroll
    for (int dt = 0; dt < 6; ++dt)
        *(f32x4*)&Po[row_id * 96 + dt * 16 + quad * 4] = Oacc[dt];
    if (quad == 0) Pl[row_id] = lacc;
}

// ---------------------------------------------------------------------------
// combine_ln (R9/R18-verified): one block per (b,t).  O=(O0+O1)/(l0+l1);
// sumsq over 16h x 96d without atomics; writes xln/rms as bf16 Xb.
// ---------------------------------------------------------------------------
__global__ __launch_bounds__(256) void combine_ln(
    const float* __restrict__ Po, const float* __restrict__ Pl,
    bf16_t* __restrict__ Xb)
{
    const int bt = blockIdx.x;            // b*Tn + t
    const int tid = threadIdx.x;
    const int hh = tid >> 4;              // head 0..15
    const int d0 = (tid & 15) * 6;        // 6 dims per thread
    const int b = bt >> 9, t = bt & 511;
    const size_t half = (size_t)Bn * Hn * Tn;
    const size_t row = ((size_t)b * Hn + hh) * Tn + t;

    const float invl = 1.0f / (Pl[row] + Pl[half + row]);

    float o[6];
    float ss = 0.f;
    {
        const float* p0 = &Po[row * 96 + d0];
        const float* p1 = &Po[(half + row) * 96 + d0];
#pragma unroll
        for (int j = 0; j < 6; ++j) {
            o[j] = (p0[j] + p1[j]) * invl;
            ss += o[j] * o[j];
        }
    }
    __shared__ float red[4];
#pragma unroll
    for (int off = 1; off < 64; off <<= 1) ss += __shfl_xor(ss, off);
    if ((tid & 63) == 0) red[tid >> 6] = ss;
    __syncthreads();
    const float tot = red[0] + red[1] + red[2] + red[3];
    const float inv = rsqrtf(tot * (1.0f / HIDn) + 1e-3f);

#pragma unroll
    for (int j = 0; j < 6; ++j) {
        const int d = d0 + j;
        const int p = d >> 5, hid = hh * 32 + (d & 31);
        Xb[((size_t)bt * Pn + p) * HIDn + hid] = (bf16_t)(o[j] * inv);
    }
}

// ---------------------------------------------------------------------------
// out_gemm (R16/R18 async structure; launch_bounds -> (256,3) so the 3rd
// resident block per CU is allowed; LDS 32KB x 3 = 96KB fits easily).
// ---------------------------------------------------------------------------
__global__ __launch_bounds__(256, 3) void out_gemm(
    const bf16_t* __restrict__ Xb, const bf16_t* __restrict__ Wb,
    float* __restrict__ out)
{
    const int n0 = blockIdx.x * 64;
    const int m0 = blockIdx.y * 64;
    const int tid = threadIdx.x;
    const int wv = tid >> 6, lane = tid & 63, l16 = lane & 15, quad = lane >> 4;

    __shared__ bf16_t Af[2][8][512];   // A frag f = wv*2+ks  (16 KB)
    __shared__ bf16_t Bf[2][8][512];   // B frag f = nt*2+ks  (16 KB)

    const bf16_t* gA0 = Xb + (size_t)(m0 + wv * 16 + l16) * HIDn + 0 * 32 + quad * 8;
    const bf16_t* gA1 = Xb + (size_t)(m0 + wv * 16 + l16) * HIDn + 1 * 32 + quad * 8;
    const bf16_t* gB0 = Wb + (size_t)(n0 + wv * 16 + l16) * HIDn + 0 * 32 + quad * 8;
    const bf16_t* gB1 = Wb + (size_t)(n0 + wv * 16 + l16) * HIDn + 1 * 32 + quad * 8;

    auto stage = [&](int kc, int buf) {
        GLDS(gA0 + kc, &Af[buf][wv * 2 + 0][0]);
        GLDS(gA1 + kc, &Af[buf][wv * 2 + 1][0]);
        GLDS(gB0 + kc, &Bf[buf][wv * 2 + 0][0]);
        GLDS(gB1 + kc, &Bf[buf][wv * 2 + 1][0]);
    };

    f32x4 acc[4];
#pragma unroll
    for (int i = 0; i < 4; ++i) acc[i] = f32x4{0.f, 0.f, 0.f, 0.f};

    stage(0, 0);

    for (int c = 0; c < 8; ++c) {
        const int buf = c & 1;
        __builtin_amdgcn_sched_barrier(0);
        __builtin_amdgcn_s_barrier();
        __builtin_amdgcn_sched_barrier(0);
        if (c + 1 < 8) {
            stage((c + 1) * 64, buf ^ 1);
            asm volatile("s_waitcnt vmcnt(4)" ::: "memory");
        } else {
            asm volatile("s_waitcnt vmcnt(0)" ::: "memory");
        }
        __builtin_amdgcn_s_barrier();
        __builtin_amdgcn_sched_barrier(0);

        __builtin_amdgcn_s_setprio(1);
#pragma unroll
        for (int ks = 0; ks < 2; ++ks) {
            bf16x8 a = *(const bf16x8*)&Af[buf][wv * 2 + ks][lane * 8];
#pragma unroll
            for (int nt = 0; nt < 4; ++nt) {
                bf16x8 bb = *(const bf16x8*)&Bf[buf][nt * 2 + ks][lane * 8];
                acc[nt] = __builtin_amdgcn_mfma_f32_16x16x32_bf16(a, bb, acc[nt], 0, 0, 0);
            }
        }
        __builtin_amdgcn_s_setprio(0);
    }

#pragma unroll
    for (int nt = 0; nt < 4; ++nt)
#pragma unroll
        for (int r = 0; r < 4; ++r) {
            const int m = m0 + wv * 16 + quad * 4 + r;
            const int n = n0 + nt * 16 + l16;
            out[(size_t)m * HIDn + n] = acc[nt][r];
        }
}

// ---------------------------------------------------------------------------
// Workspace: Qh@0 (6291456) | Kh@6291456 (12582912) | Vt@18874368 (12582912) |
// Po@31457280 (25165824) | Pl@56623104 (262144) | Xb@56885248 (6291456) |
// Wb@63176704 (524288) | Lb@63700992 (4194304)  -- total 67,895,296
// ---------------------------------------------------------------------------
extern "C" void kernel_launch(void* const* d_in, const int* in_sizes, int n_in,
                              void* d_out, int out_size, void* d_ws, size_t ws_size,
                              hipStream_t stream)
{
    const float* q    = (const float*)d_in[0];
    const float* k    = (const float*)d_in[1];
    const float* v    = (const float*)d_in[2];
    const float* bias = (const float*)d_in[3];
    const int*   outcell = (const int*)d_in[5];
    const float* lw   = (const float*)d_in[6];
    const float* W    = (const float*)d_in[8];
    const float* lnw  = (const float*)d_in[9];
    float* out = (float*)d_out;

    char* ws = (char*)d_ws;
    bf16_t* Qh   = (bf16_t*)(ws);
    bf16_t* Kh   = (bf16_t*)(ws + 6291456);
    bf16_t* Vt   = (bf16_t*)(ws + 18874368);
    float*  Po   = (float*)(ws + 31457280);
    float*  Pl   = (float*)(ws + 56623104);
    bf16_t* Xb   = (bf16_t*)(ws + 56885248);
    bf16_t* Wb   = (bf16_t*)(ws + 63176704);
    bf16_t* Lb   = (bf16_t*)(ws + 63700992);

    prep<<<dim3(NBLK_KQ + NBLK_V + NBLK_W + NBLK_LW), 256, 0, stream>>>(
        q, k, v, outcell, W, lnw, lw, Qh, Kh, Vt, Wb, Lb);
    attn_kernel<<<dim3(Hn, Bn * (Tn / 64), 2), 256, 0, stream>>>(Qh, Kh, Vt, bias, Lb, Po, Pl);
    combine_ln<<<dim3(Bn * Tn), 256, 0, stream>>>(Po, Pl, Xb);
    out_gemm<<<dim3(HIDn / 64, (Bn * Tn * Pn) / 64), 256, 0, stream>>>(Xb, Wb, out);
}